// Round 6
// baseline (168.776 us; speedup 1.0000x reference)
//
#include <hip/hip_runtime.h>
#include <math.h>

#define BB 4
#define CDIM 256
#define NN 2048
#define HEADS 8
#define DH 64
#define HIDDEN 512
#define THREEH 1536
#define QSCALE 0.18033688011112042f   // 0.125 * log2(e): softmax in exp2 domain

typedef __attribute__((ext_vector_type(8))) short bf16x8;
typedef __attribute__((ext_vector_type(4))) float f32x4;

static __device__ inline unsigned short f2bf(float f) {
    unsigned u = __float_as_uint(f);
    u += 0x7fff + ((u >> 16) & 1);
    return (unsigned short)(u >> 16);
}
#if __has_builtin(__builtin_amdgcn_cvt_pk_bf16_f32)
static __device__ inline unsigned pk2(float a, float b) {
    auto v = __builtin_amdgcn_cvt_pk_bf16_f32(a, b);
    return __builtin_bit_cast(unsigned, v);
}
#else
static __device__ inline unsigned pk2(float a, float b) {
    return (unsigned)f2bf(a) | ((unsigned)f2bf(b) << 16);
}
#endif
#if __has_builtin(__builtin_amdgcn_exp2f)
#define EXP2(x) __builtin_amdgcn_exp2f(x)
#else
#define EXP2(x) exp2f(x)
#endif
#define MFMA16(a, b, c) __builtin_amdgcn_mfma_f32_16x16x32_bf16(a, b, c, 0, 0, 0)
// XOR swizzle on tight 64-elem (128B) rows, 16B chunks, key=row&7: conflict-free b128 frags.
#define SWZC(row, ch) ((((ch) ^ ((row) & 7)) << 3))

// ---------------- prep_w: fp32 weights -> bf16 (Q rows pre-scaled by QSCALE) ----------------
__global__ __launch_bounds__(256) void prep_w(const float* __restrict__ wqkv,
                                              const float* __restrict__ wout,
                                              unsigned* __restrict__ Wqb,
                                              unsigned* __restrict__ Wob) {
    const int t = blockIdx.x * 256 + threadIdx.x;
    if (t < 98304) {
        const int e = t * 4;
        const int o = e >> 8;
        const float s = (o < HIDDEN) ? QSCALE : 1.f;
        float4 v = *(const float4*)&wqkv[e];
        Wqb[t * 2 + 0] = pk2(v.x * s, v.y * s);
        Wqb[t * 2 + 1] = pk2(v.z * s, v.w * s);
    } else {
        const int e = (t - 98304) * 4;
        float4 v = *(const float4*)&wout[e];
        Wob[(t - 98304) * 2 + 0] = pk2(v.x, v.y);
        Wob[(t - 98304) * 2 + 1] = pk2(v.z, v.w);
    }
}

// ---------------- prep_x: x[b][c][n] fp32 -> Xt[b][n][c] bf16 (one-time transpose) ----------------
__global__ __launch_bounds__(256) void prep_x(const float* __restrict__ x,
                                              unsigned short* __restrict__ Xt) {
    __shared__ float Ls[64][65];
    const int n0 = blockIdx.x * 64, c0 = blockIdx.y * 64, b = blockIdx.z;
    const int t = threadIdx.x;
    const int r16 = t >> 4, c16 = t & 15;
#pragma unroll
    for (int s = 0; s < 4; ++s) {
        const int c = s * 16 + r16;
        float4 v = *(const float4*)&x[((size_t)(b * CDIM + c0 + c)) * NN + n0 + c16 * 4];
        *(float4*)&Ls[c][c16 * 4] = v;
    }
    __syncthreads();
#pragma unroll
    for (int s = 0; s < 4; ++s) {
        const int n = s * 16 + r16;
        const int c4 = c16 * 4;
        uint2 u;
        u.x = pk2(Ls[c4][n], Ls[c4 + 1][n]);
        u.y = pk2(Ls[c4 + 2][n], Ls[c4 + 3][n]);
        *(uint2*)&Xt[((size_t)(b * NN) + n0 + n) * CDIM + c0 + c4] = u;
    }
}

// ---------------- Kernel A: qkv projection, 128x128 LDS-tiled MFMA GEMM ----------------
__global__ __launch_bounds__(256, 3) void qkv_gemm(const unsigned short* __restrict__ Xt,
                                                   const unsigned short* __restrict__ Wqb,
                                                   unsigned short* __restrict__ Qb,
                                                   unsigned short* __restrict__ Kb,
                                                   unsigned short* __restrict__ Vb) {
    __shared__ unsigned short Xs[128 * 64], Ws[128 * 64];
    const int bn0 = blockIdx.x * 128, o0 = blockIdx.y * 128;
    const int t = threadIdx.x, l = t & 63, w = t >> 6, lo = l & 15, quad = l >> 4;
    const int wo = (w >> 1) * 64, wn = (w & 1) * 64;
    const int sr = t >> 1, scb = (t & 1) * 4;
    const bool isV = (o0 >= 2 * HIDDEN);
    f32x4 acc[4][4];
#pragma unroll
    for (int i = 0; i < 4; ++i)
#pragma unroll
        for (int j = 0; j < 4; ++j) acc[i][j] = (f32x4){0.f, 0.f, 0.f, 0.f};

    for (int kc = 0; kc < CDIM; kc += 64) {
        __syncthreads();
#pragma unroll
        for (int j = 0; j < 4; ++j) {
            const int ch = scb + j;
            *(uint4*)&Xs[sr * 64 + SWZC(sr, ch)] =
                *(const uint4*)&Xt[(size_t)(bn0 + sr) * CDIM + kc + ch * 8];
            *(uint4*)&Ws[sr * 64 + SWZC(sr, ch)] =
                *(const uint4*)&Wqb[(size_t)(o0 + sr) * CDIM + kc + ch * 8];
        }
        __syncthreads();
#pragma unroll
        for (int kk = 0; kk < 2; ++kk) {
            const int swz = SWZC(lo, kk * 4 + quad);
            if (!isV) {
                bf16x8 af[4], bv[4];
#pragma unroll
                for (int ot = 0; ot < 4; ++ot) af[ot] = *(const bf16x8*)&Ws[(wo + ot * 16 + lo) * 64 + swz];
#pragma unroll
                for (int nt = 0; nt < 4; ++nt) bv[nt] = *(const bf16x8*)&Xs[(wn + nt * 16 + lo) * 64 + swz];
#pragma unroll
                for (int ot = 0; ot < 4; ++ot)
#pragma unroll
                    for (int nt = 0; nt < 4; ++nt) acc[ot][nt] = MFMA16(af[ot], bv[nt], acc[ot][nt]);
            } else {
                bf16x8 af[4], bv[4];
#pragma unroll
                for (int mt = 0; mt < 4; ++mt) af[mt] = *(const bf16x8*)&Xs[(wn + mt * 16 + lo) * 64 + swz];
#pragma unroll
                for (int ot = 0; ot < 4; ++ot) bv[ot] = *(const bf16x8*)&Ws[(wo + ot * 16 + lo) * 64 + swz];
#pragma unroll
                for (int mt = 0; mt < 4; ++mt)
#pragma unroll
                    for (int ot = 0; ot < 4; ++ot) acc[mt][ot] = MFMA16(af[mt], bv[ot], acc[mt][ot]);
            }
        }
    }
    if (!isV) {
#pragma unroll
        for (int ot = 0; ot < 4; ++ot) {
            const int og = o0 + wo + ot * 16 + quad * 4;
            const int h = (og >> 6) & 7;
            const int c0 = og & 63;
            unsigned short* dst = (og >= HIDDEN) ? Kb : Qb;
#pragma unroll
            for (int nt = 0; nt < 4; ++nt) {
                const int bn = bn0 + wn + nt * 16 + lo;
                const int b = bn >> 11, n = bn & 2047;
                uint2 u;
                u.x = pk2(acc[ot][nt][0], acc[ot][nt][1]);
                u.y = pk2(acc[ot][nt][2], acc[ot][nt][3]);
                *(uint2*)&dst[(((size_t)(b * HEADS + h)) * NN + n) * DH + c0] = u;
            }
        }
    } else {
#pragma unroll
        for (int mt = 0; mt < 4; ++mt) {
            const int bn = bn0 + wn + mt * 16 + quad * 4;
            const int b = bn >> 11, m = bn & 2047;
#pragma unroll
            for (int ot = 0; ot < 4; ++ot) {
                const int og = o0 + wo + ot * 16 + lo;
                const int h = (og >> 6) & 7;
                const int c = og & 63;
                uint2 u;
                u.x = pk2(acc[mt][ot][0], acc[mt][ot][1]);
                u.y = pk2(acc[mt][ot][2], acc[mt][ot][3]);
                *(uint2*)&Vb[(((size_t)(b * HEADS + h)) * DH + c) * NN + m] = u;
            }
        }
    }
}

// ---------------- Kernel B: flash attention, m-split across waves ----------------
// Each wave: private 64-m chunk per iter (m = m0 + 64w), K/V A-frags DIRECT from global,
// independent online softmax (per-wave m_i/l_i), P via wave-private LDS. No in-loop barriers.
// Epilogue: 4-way partial merge (flash-decoding style) through LDS.
__global__ __launch_bounds__(256, 2) void flash_attn(const unsigned short* __restrict__ Qb,
                                                     const unsigned short* __restrict__ Kb,
                                                     const unsigned short* __restrict__ Vb,
                                                     unsigned short* __restrict__ Yb) {
    __shared__ char smem[71680];   // [0,32K): P (4x8KB wave-private) ; aliased by merge Opart
    const int flat = blockIdx.x;
    const int rest = flat >> 3;
    const int bh = ((rest & 3) << 3) | (flat & 7);   // XCD-local (b,h)
    const int q0 = (rest >> 2) * 64;
    const int b = bh >> 3, h = bh & 7;
    const int t = threadIdx.x, l = t & 63, w = t >> 6, lo = l & 15, quad = l >> 4;
    unsigned short* Pw = (unsigned short*)smem + (size_t)w * 4096;   // 8 KB per wave
    float* OpF = (float*)smem;                        // merge: [w][q][68] fp32
    float* mM = (float*)(smem + 69632);               // [w][64]
    float* mL = mM + 256;                             // [w][64]
    const unsigned short* Qp = Qb + (size_t)bh * NN * DH;
    const unsigned short* Kp = Kb + (size_t)bh * NN * DH;
    const unsigned short* Vp = Vb + (size_t)bh * DH * NN;
    const int key = lo & 7;

    bf16x8 bQ[4][2];
#pragma unroll
    for (int qt = 0; qt < 4; ++qt)
#pragma unroll
        for (int hh = 0; hh < 2; ++hh)
            bQ[qt][hh] = *(const bf16x8*)&Qp[(size_t)(q0 + qt * 16 + lo) * DH + hh * 32 + quad * 8];

    f32x4 O[4][4];
#pragma unroll
    for (int i = 0; i < 4; ++i)
#pragma unroll
        for (int j = 0; j < 4; ++j) O[i][j] = (f32x4){0.f, 0.f, 0.f, 0.f};
    float m_i[4], l_i[4];
#pragma unroll
    for (int qt = 0; qt < 4; ++qt) { m_i[qt] = -INFINITY; l_i[qt] = 0.f; }

#pragma unroll 1
    for (int m0 = 0; m0 < NN; m0 += 256) {
        const int mw = m0 + w * 64;
        // ---- K A-frags direct from global (rows m, c-contig) ----
        bf16x8 aK0[4], aK1[4];
#pragma unroll
        for (int nt = 0; nt < 4; ++nt) {
            const unsigned short* kr = Kp + (size_t)(mw + nt * 16 + lo) * DH + quad * 8;
            aK0[nt] = *(const bf16x8*)kr;
            aK1[nt] = *(const bf16x8*)(kr + 32);
        }
        // ---- S^T[m 64][q 64] : 32 MFMAs ----
        f32x4 S[4][4];
#pragma unroll
        for (int nt = 0; nt < 4; ++nt)
#pragma unroll
            for (int qt = 0; qt < 4; ++qt) {
                f32x4 z = (f32x4){0.f, 0.f, 0.f, 0.f};
                z = MFMA16(aK0[nt], bQ[qt][0], z);
                z = MFMA16(aK1[nt], bQ[qt][1], z);
                S[nt][qt] = z;
            }
        // ---- per-wave online softmax over this wave's 64 m ----
        float alpha[4];
#pragma unroll
        for (int qt = 0; qt < 4; ++qt) {
            float mx;
            {
                f32x4 mm;
#pragma unroll
                for (int i = 0; i < 4; ++i)
                    mm[i] = fmaxf(fmaxf(S[0][qt][i], S[1][qt][i]), fmaxf(S[2][qt][i], S[3][qt][i]));
                mx = fmaxf(fmaxf(mm[0], mm[1]), fmaxf(mm[2], mm[3]));
            }
            mx = fmaxf(mx, __shfl_xor(mx, 16));
            mx = fmaxf(mx, __shfl_xor(mx, 32));
            const float mn = fmaxf(m_i[qt], mx);
            alpha[qt] = EXP2(m_i[qt] - mn);
            m_i[qt] = mn;
            float ls = 0.f;
            const int prow = (qt * 16 + lo) * 64;
#pragma unroll
            for (int nt = 0; nt < 4; ++nt) {
                f32x4 p;
#pragma unroll
                for (int i = 0; i < 4; ++i) p[i] = EXP2(S[nt][qt][i] - mn);
                ls += (p[0] + p[1]) + (p[2] + p[3]);
                uint2 u;
                u.x = pk2(p[0], p[1]);
                u.y = pk2(p[2], p[3]);
                *(uint2*)&Pw[prow + (((nt * 2 + (quad >> 1)) ^ key) << 3) + (quad & 1) * 4] = u;
            }
            ls += __shfl_xor(ls, 16);
            ls += __shfl_xor(ls, 32);
            l_i[qt] = l_i[qt] * alpha[qt] + ls;
        }
        asm volatile("s_waitcnt lgkmcnt(0)" ::: "memory");   // P write->read, same wave
        // ---- rescale O (skip when all alphas == 1: max already settled) ----
        const float am = fminf(fminf(alpha[0], alpha[1]), fminf(alpha[2], alpha[3]));
        if (__ballot(am < 1.f)) {
#pragma unroll
            for (int ct = 0; ct < 4; ++ct)
#pragma unroll
                for (int qt = 0; qt < 4; ++qt) O[ct][qt] *= alpha[qt];
        }
        // ---- O^T += V^T P^T : V A-frags direct from global, 32 MFMAs ----
#pragma unroll
        for (int kk = 0; kk < 2; ++kk) {
            bf16x8 pb[4];
#pragma unroll
            for (int qt = 0; qt < 4; ++qt)
                pb[qt] = *(const bf16x8*)&Pw[(qt * 16 + lo) * 64 + (((kk * 4 + quad) ^ key) << 3)];
            bf16x8 aV[4];
#pragma unroll
            for (int ct = 0; ct < 4; ++ct)
                aV[ct] = *(const bf16x8*)&Vp[(size_t)(ct * 16 + lo) * NN + mw + kk * 32 + quad * 8];
#pragma unroll
            for (int ct = 0; ct < 4; ++ct)
#pragma unroll
                for (int qt = 0; qt < 4; ++qt) O[ct][qt] = MFMA16(aV[ct], pb[qt], O[ct][qt]);
        }
    }

    // ---- merge 4 per-wave partials ----
    if (quad == 0) {
#pragma unroll
        for (int qt = 0; qt < 4; ++qt) {
            mM[w * 64 + qt * 16 + lo] = m_i[qt];
            mL[w * 64 + qt * 16 + lo] = l_i[qt];
        }
    }
    __syncthreads();   // all PV reads done (P alias safe) + ml visible
    float fsc[4];
#pragma unroll
    for (int qt = 0; qt < 4; ++qt) {
        const int qi = qt * 16 + lo;
        float ms = fmaxf(fmaxf(mM[qi], mM[64 + qi]), fmaxf(mM[128 + qi], mM[192 + qi]));
        fsc[qt] = EXP2(m_i[qt] - ms);
    }
#pragma unroll
    for (int ct = 0; ct < 4; ++ct)
#pragma unroll
        for (int qt = 0; qt < 4; ++qt) {
            f32x4 v = O[ct][qt] * fsc[qt];
            *(f32x4*)&OpF[(size_t)(w * 64 + qt * 16 + lo) * 68 + ct * 16 + quad * 4] = v;
        }
    __syncthreads();
    // each wave sums c-slice [16w,16w+16) over 4 partials; thread handles q = l
    const int qi = l;
    float ms = fmaxf(fmaxf(mM[qi], mM[64 + qi]), fmaxf(mM[128 + qi], mM[192 + qi]));
    float lstar = EXP2(mM[qi] - ms) * mL[qi] + EXP2(mM[64 + qi] - ms) * mL[64 + qi] +
                  EXP2(mM[128 + qi] - ms) * mL[128 + qi] + EXP2(mM[192 + qi] - ms) * mL[192 + qi];
    const float inv = 1.f / lstar;
    unsigned uo[8];
#pragma unroll
    for (int j = 0; j < 4; ++j) {
        f32x4 s = (f32x4){0.f, 0.f, 0.f, 0.f};
#pragma unroll
        for (int wp = 0; wp < 4; ++wp)
            s += *(const f32x4*)&OpF[(size_t)(wp * 64 + qi) * 68 + 16 * w + j * 4];
        s *= inv;
        uo[2 * j]     = pk2(s[0], s[1]);
        uo[2 * j + 1] = pk2(s[2], s[3]);
    }
    unsigned short* yp = Yb + ((size_t)(b * NN) + q0 + qi) * HIDDEN + h * DH + 16 * w;
    *(uint4*)&yp[0] = *(uint4*)&uo[0];
    *(uint4*)&yp[8] = *(uint4*)&uo[4];
}

// ---------------- Kernel C: out projection, 128x64 LDS-tiled MFMA GEMM + bias ----------------
__global__ __launch_bounds__(256, 4) void out_gemm(const unsigned short* __restrict__ Yb,
                                                   const unsigned short* __restrict__ Wob,
                                                   const float* __restrict__ bias,
                                                   float* __restrict__ out) {
    __shared__ unsigned short Ys[128 * 64], Wos[64 * 64];
    const int bn0 = blockIdx.x * 128, o0 = blockIdx.y * 64;
    const int t = threadIdx.x, l = t & 63, w = t >> 6, lo = l & 15, quad = l >> 4;
    const int wn = w * 32;
    const int sr = t >> 1, scb = (t & 1) * 4;
    const int sr2 = t >> 2, scb2 = (t & 3) * 2;
    f32x4 acc[2][4];
#pragma unroll
    for (int i = 0; i < 2; ++i)
#pragma unroll
        for (int j = 0; j < 4; ++j) acc[i][j] = (f32x4){0.f, 0.f, 0.f, 0.f};

    for (int kc = 0; kc < HIDDEN; kc += 64) {
        __syncthreads();
#pragma unroll
        for (int j = 0; j < 4; ++j) {
            const int ch = scb + j;
            *(uint4*)&Ys[sr * 64 + SWZC(sr, ch)] =
                *(const uint4*)&Yb[(size_t)(bn0 + sr) * HIDDEN + kc + ch * 8];
        }
#pragma unroll
        for (int j = 0; j < 2; ++j) {
            const int ch = scb2 + j;
            *(uint4*)&Wos[sr2 * 64 + SWZC(sr2, ch)] =
                *(const uint4*)&Wob[(size_t)(o0 + sr2) * HIDDEN + kc + ch * 8];
        }
        __syncthreads();
#pragma unroll
        for (int kk = 0; kk < 2; ++kk) {
            const int swz = SWZC(lo, kk * 4 + quad);
            bf16x8 bv[4];
#pragma unroll
            for (int ot = 0; ot < 4; ++ot) bv[ot] = *(const bf16x8*)&Wos[(ot * 16 + lo) * 64 + swz];
#pragma unroll
            for (int mt = 0; mt < 2; ++mt) {
                bf16x8 av = *(const bf16x8*)&Ys[(wn + mt * 16 + lo) * 64 + swz];
#pragma unroll
                for (int ot = 0; ot < 4; ++ot) acc[mt][ot] = MFMA16(av, bv[ot], acc[mt][ot]);
            }
        }
    }
#pragma unroll
    for (int mt = 0; mt < 2; ++mt) {
        const int bn = bn0 + wn + mt * 16 + quad * 4;
        const int b = bn >> 11, n = bn & 2047;
#pragma unroll
        for (int ot = 0; ot < 4; ++ot) {
            const int o = o0 + ot * 16 + lo;
            *(f32x4*)&out[((size_t)(b * CDIM + o)) * NN + n] = acc[mt][ot] + bias[o];
        }
    }
}

extern "C" void kernel_launch(void* const* d_in, const int* in_sizes, int n_in,
                              void* d_out, int out_size, void* d_ws, size_t ws_size,
                              hipStream_t stream) {
    const float* x     = (const float*)d_in[0];
    const float* w_qkv = (const float*)d_in[1];
    const float* w_out = (const float*)d_in[2];
    const float* b_out = (const float*)d_in[3];
    float* out = (float*)d_out;

    unsigned short* Wqb = (unsigned short*)d_ws;
    unsigned short* Wob = Wqb + (size_t)THREEH * CDIM;
    unsigned short* Xt  = Wob + (size_t)CDIM * HIDDEN;
    unsigned short* Qb  = Xt + (size_t)BB * NN * CDIM;
    unsigned short* Kb  = Qb + (size_t)BB * HEADS * NN * DH;
    unsigned short* Vb  = Kb + (size_t)BB * HEADS * NN * DH;
    unsigned short* Yb  = Vb + (size_t)BB * HEADS * DH * NN;

    prep_w<<<512, 256, 0, stream>>>(w_qkv, w_out, (unsigned*)Wqb, (unsigned*)Wob);
    prep_x<<<dim3(NN / 64, CDIM / 64, BB), 256, 0, stream>>>(x, Xt);
    qkv_gemm<<<dim3(BB * NN / 128, THREEH / 128), 256, 0, stream>>>(Xt, Wqb, Qb, Kb, Vb);
    flash_attn<<<1024, 256, 0, stream>>>(Qb, Kb, Vb, Yb);
    out_gemm<<<dim3(BB * NN / 128, CDIM / 64), 256, 0, stream>>>(Yb, Wob, b_out, out);
}